// Round 3
// baseline (243.715 us; speedup 1.0000x reference)
//
#include <hip/hip_runtime.h>
#include <hip/hip_fp8.h>

// Problem geometry (fixed by the reference):
//   B=4, H=32, S=8192, D=128
//   cur   : [B,H,1,D] f32      (d_in[0], 16384 elems)
//   cache : [B,H,S,D] f32      (d_in[1], 134217728 elems) — fp8-representable values
//   s_in  : [1] f32            (d_in[2])
//   s_out : [1] f32            (d_in[3])
//   idx   : [1] i32            (d_in[4])
// out = (cache with row pos=clip(idx-1,0,S-1) replaced by fp8(cur/s_in)) * s_out
//
// Strategy: kernel 1 = pure streaming out = cache * s_out (no branches, 4x
// unrolled independent float4 loads, nontemporal). kernel 2 = tiny patch of
// the 128 rows at s=pos (16K elements), runs after on the same stream.

#define S_LEN 8192
#define D_LEN 128
#define F4_PER_ROW 32        // D/4

// Native clang vector type — required by __builtin_nontemporal_* (HIP's
// float4 is a class and is rejected).
typedef float f32x4 __attribute__((ext_vector_type(4)));

__device__ __forceinline__ float fp8_qdq(float x) {
    __hip_fp8_e4m3 q(x);     // f32 -> e4m3fn (RNE) -> f32
    return (float)q;
}

__global__ __launch_bounds__(256) void kv_scale_copy_kernel(
    const f32x4* __restrict__ cache4,
    const float* __restrict__ s_out,
    f32x4* __restrict__ out4,
    long long n4)
{
    const float so = s_out[0];
    const long long stride = (long long)gridDim.x * blockDim.x;
    long long i = (long long)blockIdx.x * blockDim.x + threadIdx.x;

    // n4 / stride == 64 for the shipped launch config -> 16 unrolled iters, no tail.
    for (; i + 3 * stride < n4; i += 4 * stride) {
        f32x4 a = __builtin_nontemporal_load(&cache4[i]);
        f32x4 b = __builtin_nontemporal_load(&cache4[i + stride]);
        f32x4 c = __builtin_nontemporal_load(&cache4[i + 2 * stride]);
        f32x4 d = __builtin_nontemporal_load(&cache4[i + 3 * stride]);
        a *= so; b *= so; c *= so; d *= so;
        __builtin_nontemporal_store(a, &out4[i]);
        __builtin_nontemporal_store(b, &out4[i + stride]);
        __builtin_nontemporal_store(c, &out4[i + 2 * stride]);
        __builtin_nontemporal_store(d, &out4[i + 3 * stride]);
    }
    for (; i < n4; i += stride) {
        f32x4 a = __builtin_nontemporal_load(&cache4[i]);
        a *= so;
        __builtin_nontemporal_store(a, &out4[i]);
    }
}

// One float4 per thread over the B*H*D patched elements (4096 float4s).
__global__ __launch_bounds__(256) void kv_patch_kernel(
    const float* __restrict__ cur,
    const float* __restrict__ s_in,
    const float* __restrict__ s_out,
    const int* __restrict__ idx,
    f32x4* __restrict__ out4)
{
    const int tid = blockIdx.x * blockDim.x + threadIdx.x;  // [0, 4096)
    const int bh = tid >> 5;                 // [0, B*H)
    const int f  = tid & (F4_PER_ROW - 1);   // float4 index within row

    int pos = idx[0] - 1;
    pos = pos < 0 ? 0 : (pos > S_LEN - 1 ? S_LEN - 1 : pos);
    const float si = s_in[0];
    const float so = s_out[0];

    const f32x4 c = ((const f32x4*)cur)[(bh << 5) + f];
    f32x4 v;
    v.x = fp8_qdq(c.x / si) * so;
    v.y = fp8_qdq(c.y / si) * so;
    v.z = fp8_qdq(c.z / si) * so;
    v.w = fp8_qdq(c.w / si) * so;
    out4[((long long)bh * S_LEN + pos) * F4_PER_ROW + f] = v;
}

extern "C" void kernel_launch(void* const* d_in, const int* in_sizes, int n_in,
                              void* d_out, int out_size, void* d_ws, size_t ws_size,
                              hipStream_t stream)
{
    const float* cur   = (const float*)d_in[0];
    const float* cache = (const float*)d_in[1];
    const float* s_in  = (const float*)d_in[2];
    const float* s_out = (const float*)d_in[3];
    const int*   idx   = (const int*)d_in[4];
    float* out = (float*)d_out;

    const long long n4 = (long long)out_size / 4;   // 33,554,432 float4s

    kv_scale_copy_kernel<<<2048, 256, 0, stream>>>(
        (const f32x4*)cache, s_out, (f32x4*)out, n4);

    // 4096 float4s to patch: 16 blocks x 256 threads
    kv_patch_kernel<<<16, 256, 0, stream>>>(
        cur, s_in, s_out, idx, (f32x4*)out);
}

// Round 4
// 180.376 us; speedup vs baseline: 1.3512x; 1.3512x over previous
//
#include <hip/hip_runtime.h>
#include <hip/hip_fp8.h>

// Problem geometry (fixed by the reference):
//   B=4, H=32, S=8192, D=128
//   cur   : [B,H,1,D] f32      (d_in[0], 16384 elems)
//   cache : [B,H,S,D] f32      (d_in[1], 134217728 elems) — fp8-representable values
//   s_in  : [1] f32            (d_in[2])
//   s_out : [1] f32            (d_in[3])
//   idx   : [1] i32            (d_in[4])
// out = (cache with row pos=clip(idx-1,0,S-1) replaced by fp8(cur/s_in)) * s_out
//
// Round-4 strategy: flat launch, ONE float4 per thread (no grid-stride loop,
// no unroll, no nontemporal) — mimic the 6.3 TB/s float4-copy ubench shape
// exactly, with the scale and the (rare) patch branch fused in.

#define S_LEN 8192
#define D_LEN 128
#define F4_PER_ROW 32        // D/4

typedef float f32x4 __attribute__((ext_vector_type(4)));

__device__ __forceinline__ float fp8_qdq(float x) {
    __hip_fp8_e4m3 q(x);     // f32 -> e4m3fn (RNE) -> f32
    return (float)q;
}

__global__ __launch_bounds__(256) void kv_kernel(
    const f32x4* __restrict__ cache4,
    const float* __restrict__ cur,
    const float* __restrict__ s_in,
    const float* __restrict__ s_out,
    const int* __restrict__ idx,
    f32x4* __restrict__ out4)
{
    const int i = blockIdx.x * 256 + threadIdx.x;   // [0, 33554432): fits int

    f32x4 v = cache4[i];                            // issue the load first

    const float so = s_out[0];
    int pos = idx[0] - 1;
    pos = pos < 0 ? 0 : (pos > S_LEN - 1 ? S_LEN - 1 : pos);

    const int s = (i >> 5) & (S_LEN - 1);           // seq position of this float4
    if (s == pos) {
        // patched row: 4096 of 33.5M threads take this
        const int bh = i >> 18;                     // i >> (5 + 13) = b*H + h
        const int f  = i & (F4_PER_ROW - 1);
        const f32x4 c = ((const f32x4*)cur)[(bh << 5) + f];
        const float si = s_in[0];
        v.x = fp8_qdq(c.x / si);
        v.y = fp8_qdq(c.y / si);
        v.z = fp8_qdq(c.z / si);
        v.w = fp8_qdq(c.w / si);
    }
    v *= so;
    out4[i] = v;
}

extern "C" void kernel_launch(void* const* d_in, const int* in_sizes, int n_in,
                              void* d_out, int out_size, void* d_ws, size_t ws_size,
                              hipStream_t stream)
{
    const float* cur   = (const float*)d_in[0];
    const float* cache = (const float*)d_in[1];
    const float* s_in  = (const float*)d_in[2];
    const float* s_out = (const float*)d_in[3];
    const int*   idx   = (const int*)d_in[4];
    float* out = (float*)d_out;

    const int n4 = out_size / 4;                    // 33,554,432 float4s
    const int blocks = n4 / 256;                    // 131072 blocks, flat

    kv_kernel<<<blocks, 256, 0, stream>>>(
        (const f32x4*)cache, cur, s_in, s_out, idx, (f32x4*)out);
}

// Round 5
// 168.809 us; speedup vs baseline: 1.4437x; 1.0685x over previous
//
#include <hip/hip_runtime.h>
#include <hip/hip_fp8.h>

// Problem geometry (fixed by the reference):
//   B=4, H=32, S=8192, D=128
//   cur   : [B,H,1,D] f32      (d_in[0], 16384 elems)
//   cache : [B,H,S,D] f32      (d_in[1], 134217728 elems) — fp8-representable values
//   s_in  : [1] f32            (d_in[2])
//   s_out : [1] f32            (d_in[3])
//   idx   : [1] i32            (d_in[4])
// out = (cache with row pos=clip(idx-1,0,S-1) replaced by fp8(cur/s_in)) * s_out
//
// Round-5: round-4 flat shape (one float4/thread, 131072x256) + nontemporal
// load/store hints on the streaming path (zero-reuse data; bypass cache).

#define S_LEN 8192
#define D_LEN 128
#define F4_PER_ROW 32        // D/4

typedef float f32x4 __attribute__((ext_vector_type(4)));

__device__ __forceinline__ float fp8_qdq(float x) {
    __hip_fp8_e4m3 q(x);     // f32 -> e4m3fn (RNE) -> f32
    return (float)q;
}

__global__ __launch_bounds__(256) void kv_kernel(
    const f32x4* __restrict__ cache4,
    const float* __restrict__ cur,
    const float* __restrict__ s_in,
    const float* __restrict__ s_out,
    const int* __restrict__ idx,
    f32x4* __restrict__ out4)
{
    const int i = blockIdx.x * 256 + threadIdx.x;   // [0, 33554432): fits int

    f32x4 v = __builtin_nontemporal_load(&cache4[i]);   // issue the load first

    const float so = s_out[0];
    int pos = idx[0] - 1;
    pos = pos < 0 ? 0 : (pos > S_LEN - 1 ? S_LEN - 1 : pos);

    const int s = (i >> 5) & (S_LEN - 1);           // seq position of this float4
    if (s == pos) {
        // patched row: 4096 of 33.5M threads take this
        const int bh = i >> 18;                     // i >> (5 + 13) = b*H + h
        const int f  = i & (F4_PER_ROW - 1);
        const f32x4 c = ((const f32x4*)cur)[(bh << 5) + f];
        const float si = s_in[0];
        v.x = fp8_qdq(c.x / si);
        v.y = fp8_qdq(c.y / si);
        v.z = fp8_qdq(c.z / si);
        v.w = fp8_qdq(c.w / si);
    }
    v *= so;
    __builtin_nontemporal_store(v, &out4[i]);
}

extern "C" void kernel_launch(void* const* d_in, const int* in_sizes, int n_in,
                              void* d_out, int out_size, void* d_ws, size_t ws_size,
                              hipStream_t stream)
{
    const float* cur   = (const float*)d_in[0];
    const float* cache = (const float*)d_in[1];
    const float* s_in  = (const float*)d_in[2];
    const float* s_out = (const float*)d_in[3];
    const int*   idx   = (const int*)d_in[4];
    float* out = (float*)d_out;

    const int n4 = out_size / 4;                    // 33,554,432 float4s
    const int blocks = n4 / 256;                    // 131072 blocks, flat

    kv_kernel<<<blocks, 256, 0, stream>>>(
        (const f32x4*)cache, cur, s_in, s_out, idx, (f32x4*)out);
}